// Round 1
// baseline (207.157 us; speedup 1.0000x reference)
//
#include <hip/hip_runtime.h>
#include <hip/hip_bf16.h>

typedef unsigned short u16;
typedef unsigned int   u32;
typedef __attribute__((ext_vector_type(8))) short bf16x8;
typedef __attribute__((ext_vector_type(4))) float f32x4;

#define SEQ     2048
#define DM      1024
#define NH      16
#define DKH     64
#define MROWS   4096                 // B*S
#define PER_SRC 4194304              // MROWS*DM

__device__ __forceinline__ u16 f2bf(float f) {
    union { float f; u32 u; } c; c.f = f;
    return (u16)((c.u + 0x7fffu + ((c.u >> 16) & 1u)) >> 16);
}

__device__ __forceinline__ void gload_lds16(const void* g, void* l) {
    __builtin_amdgcn_global_load_lds((__attribute__((address_space(1))) void*)g,
                                     (__attribute__((address_space(3))) void*)l,
                                     16, 0, 0);
}

// ---------------- cast q/k/v fp32 -> bf16 ----------------
__global__ void cast_qkv(const float* __restrict__ q, const float* __restrict__ k,
                         const float* __restrict__ v, u16* __restrict__ xb) {
    const float* src = (blockIdx.y == 0) ? q : (blockIdx.y == 1) ? k : v;
    u16* dst = xb + (size_t)blockIdx.y * PER_SRC;
    size_t i = ((size_t)blockIdx.x * 256 + threadIdx.x) * 8;
    float4 a = *(const float4*)(src + i);
    float4 b = *(const float4*)(src + i + 4);
    bf16x8 o;
    o[0] = (short)f2bf(a.x); o[1] = (short)f2bf(a.y);
    o[2] = (short)f2bf(a.z); o[3] = (short)f2bf(a.w);
    o[4] = (short)f2bf(b.x); o[5] = (short)f2bf(b.y);
    o[6] = (short)f2bf(b.z); o[7] = (short)f2bf(b.w);
    *(bf16x8*)(dst + i) = o;
}

// ---------------- transpose-cast W [K,N] f32 -> Wt [N,K] bf16 ----------------
__global__ void wtrans(const float* __restrict__ Wq, const float* __restrict__ Wo,
                       u16* __restrict__ Wqt, u16* __restrict__ Wot) {
    const float* W = blockIdx.y ? Wo : Wq;
    u16* Wt       = blockIdx.y ? Wot : Wqt;
    int k0 = (blockIdx.x & 15) * 64;
    int n0 = (blockIdx.x >> 4) * 64;
    __shared__ __align__(16) float t[64][68];
    int tid = threadIdx.x;
    int r = tid >> 2, cs = (tid & 3) * 16;
    #pragma unroll
    for (int j = 0; j < 4; ++j) {
        float4 vv = *(const float4*)(W + (size_t)(k0 + r) * DM + n0 + cs + j * 4);
        *(float4*)&t[r][cs + j * 4] = vv;
    }
    __syncthreads();
    bf16x8 o0, o1;
    #pragma unroll
    for (int j = 0; j < 8; ++j) o0[j] = (short)f2bf(t[cs + j][r]);
    #pragma unroll
    for (int j = 0; j < 8; ++j) o1[j] = (short)f2bf(t[cs + 8 + j][r]);
    u16* dst = Wt + (size_t)(n0 + r) * DM + k0 + cs;
    *(bf16x8*)(dst)     = o0;
    *(bf16x8*)(dst + 8) = o1;
}

// ---------------- transpose vh [BH,S,64] -> vt [BH,64,S] ----------------
__global__ void vtrans(const u16* __restrict__ vh, u16* __restrict__ vt) {
    int bh = blockIdx.y, st = blockIdx.x;
    __shared__ u16 t[64][72];
    int tid = threadIdx.x;
    int r = tid >> 2, cs = (tid & 3) * 16;
    const u16* src = vh + ((size_t)bh * SEQ + st * 64 + r) * DKH + cs;
    bf16x8 v0 = *(const bf16x8*)(src);
    bf16x8 v1 = *(const bf16x8*)(src + 8);
    #pragma unroll
    for (int j = 0; j < 8; ++j) { t[r][cs + j] = (u16)v0[j]; t[r][cs + 8 + j] = (u16)v1[j]; }
    __syncthreads();
    bf16x8 o0, o1;
    #pragma unroll
    for (int j = 0; j < 8; ++j) o0[j] = (short)t[cs + j][r];
    #pragma unroll
    for (int j = 0; j < 8; ++j) o1[j] = (short)t[cs + 8 + j][r];
    u16* dst = vt + ((size_t)bh * DKH + r) * SEQ + st * 64 + cs;
    *(bf16x8*)(dst)     = o0;
    *(bf16x8*)(dst + 8) = o1;
}

// ---------------- GEMM: C = A[M,1024] * Bt[N=1024,K=1024]^T + bias ----------------
// OUT_MODE 0: write bf16 scattered to head layout [B,H,S,64] (dst = base + z*PER_SRC)
// OUT_MODE 1: write fp32 flat [M,1024]
template<int OUT_MODE>
__global__ __launch_bounds__(256)
void gemm_bt(const u16* __restrict__ Abase, const u16* __restrict__ Bt,
             const float* __restrict__ bias, void* __restrict__ outbase)
{
    __shared__ __align__(16) u16 Alds[128 * 64];
    __shared__ __align__(16) u16 Blds[128 * 64];

    const int tid  = threadIdx.x;
    const int wave = tid >> 6;
    const int lane = tid & 63;
    const int low4 = lane & 15;
    const int quad = lane >> 4;
    const int m0 = (blockIdx.x >> 3) * 128;
    const int n0 = (blockIdx.x & 7) * 128;
    const int wm = (wave >> 1) * 64, wn = (wave & 1) * 64;

    const u16* A = Abase + (size_t)blockIdx.z * PER_SRC;

    f32x4 acc[4][4] = {};

    for (int kt = 0; kt < DM / 64; ++kt) {
        #pragma unroll
        for (int it = 0; it < 4; ++it) {
            int seg  = it * 256 + tid;
            int row  = seg >> 3;
            int slot = seg & 7;
            int ss   = slot ^ (row & 7);   // pre-swizzled source (involution)
            gload_lds16(A  + (size_t)(m0 + row) * DM + kt * 64 + ss * 8,
                        &Alds[(it * 256 + wave * 64) * 8]);
            gload_lds16(Bt + (size_t)(n0 + row) * DM + kt * 64 + ss * 8,
                        &Blds[(it * 256 + wave * 64) * 8]);
        }
        __syncthreads();
        #pragma unroll
        for (int kk = 0; kk < 2; ++kk) {
            bf16x8 af[4], bfr[4];
            #pragma unroll
            for (int mi = 0; mi < 4; ++mi) {
                int row = wm + mi * 16 + low4;
                af[mi] = *(const bf16x8*)&Alds[row * 64 + (((kk * 4 + quad) ^ (row & 7)) * 8)];
            }
            #pragma unroll
            for (int ni = 0; ni < 4; ++ni) {
                int row = wn + ni * 16 + low4;
                bfr[ni] = *(const bf16x8*)&Blds[row * 64 + (((kk * 4 + quad) ^ (row & 7)) * 8)];
            }
            #pragma unroll
            for (int mi = 0; mi < 4; ++mi)
                #pragma unroll
                for (int ni = 0; ni < 4; ++ni)
                    acc[mi][ni] = __builtin_amdgcn_mfma_f32_16x16x32_bf16(
                        af[mi], bfr[ni], acc[mi][ni], 0, 0, 0);
        }
        __syncthreads();
    }

    #pragma unroll
    for (int mi = 0; mi < 4; ++mi) {
        #pragma unroll
        for (int ni = 0; ni < 4; ++ni) {
            int n = n0 + wn + ni * 16 + low4;
            float bv = bias[n];
            #pragma unroll
            for (int j = 0; j < 4; ++j) {
                int m = m0 + wm + mi * 16 + quad * 4 + j;
                float val = acc[mi][ni][j] + bv;
                if (OUT_MODE == 0) {
                    u16* dst = (u16*)outbase + (size_t)blockIdx.z * PER_SRC;
                    int b = m >> 11, s = m & (SEQ - 1);
                    int h = n >> 6, dd = n & 63;
                    dst[(size_t)(b * NH + h) * (SEQ * DKH) + (size_t)s * DKH + dd] = f2bf(val);
                } else {
                    ((float*)outbase)[(size_t)m * DM + n] = val;
                }
            }
        }
    }
}

// ---------------- flash attention: per (bh, qtile of 64 rows) ----------------
__global__ __launch_bounds__(256)
void attn(const u16* __restrict__ qh, const u16* __restrict__ kh,
          const u16* __restrict__ vt, u16* __restrict__ ao)
{
    __shared__ __align__(16) u16 Klds[64 * 64];
    __shared__ __align__(16) u16 Vlds[64 * 64];
    __shared__ __align__(16) u16 Plds[4][16 * 64];

    const int tid  = threadIdx.x;
    const int w    = tid >> 6;
    const int lane = tid & 63;
    const int low4 = lane & 15;
    const int quad = lane >> 4;
    const int qt = blockIdx.x, bh = blockIdx.y;
    const int b = bh >> 4, h = bh & 15;
    const int q_row = qt * 64 + w * 16 + low4;

    bf16x8 qf[2];
    #pragma unroll
    for (int kk = 0; kk < 2; ++kk)
        qf[kk] = *(const bf16x8*)&qh[((size_t)bh * SEQ + q_row) * DKH + kk * 32 + quad * 8];

    float m_r[4] = {-1e30f, -1e30f, -1e30f, -1e30f};
    float l_r[4] = {0.f, 0.f, 0.f, 0.f};
    f32x4 o_acc[4] = {};

    for (int kt = 0; kt < SEQ / 64; ++kt) {
        #pragma unroll
        for (int it = 0; it < 2; ++it) {
            int seg  = it * 256 + tid;
            int row  = seg >> 3;
            int slot = seg & 7;
            int ss   = slot ^ (row & 7);
            gload_lds16(kh + ((size_t)bh * SEQ + kt * 64 + row) * DKH + ss * 8,
                        &Klds[(it * 256 + w * 64) * 8]);
            gload_lds16(vt + ((size_t)bh * DKH + row) * SEQ + kt * 64 + ss * 8,
                        &Vlds[(it * 256 + w * 64) * 8]);
        }
        __syncthreads();

        // S = Q K^T
        f32x4 s_acc[4] = {};
        #pragma unroll
        for (int kk = 0; kk < 2; ++kk) {
            #pragma unroll
            for (int tb = 0; tb < 4; ++tb) {
                int row = tb * 16 + low4;
                bf16x8 kf = *(const bf16x8*)&Klds[row * 64 + (((kk * 4 + quad) ^ (row & 7)) * 8)];
                s_acc[tb] = __builtin_amdgcn_mfma_f32_16x16x32_bf16(qf[kk], kf, s_acc[tb], 0, 0, 0);
            }
        }
        #pragma unroll
        for (int tb = 0; tb < 4; ++tb) s_acc[tb] *= 0.125f;   // 1/sqrt(64)

        // online softmax (row q = quad*4+r; 16 t-values per row spread over low4)
        #pragma unroll
        for (int r = 0; r < 4; ++r) {
            float mx = fmaxf(fmaxf(s_acc[0][r], s_acc[1][r]),
                             fmaxf(s_acc[2][r], s_acc[3][r]));
            #pragma unroll
            for (int off = 1; off < 16; off <<= 1) mx = fmaxf(mx, __shfl_xor(mx, off));
            float mnew = fmaxf(m_r[r], mx);
            float fac  = __expf(m_r[r] - mnew);
            m_r[r] = mnew;
            float rs = 0.f;
            #pragma unroll
            for (int tb = 0; tb < 4; ++tb) {
                float p = __expf(s_acc[tb][r] - mnew);
                s_acc[tb][r] = p;
                rs += p;
            }
            #pragma unroll
            for (int off = 1; off < 16; off <<= 1) rs += __shfl_xor(rs, off);
            l_r[r] = l_r[r] * fac + rs;
            #pragma unroll
            for (int db = 0; db < 4; ++db) o_acc[db][r] *= fac;
        }

        // P -> LDS (swizzled, per-wave region)
        #pragma unroll
        for (int tb = 0; tb < 4; ++tb)
            #pragma unroll
            for (int r = 0; r < 4; ++r) {
                int qq = quad * 4 + r;
                int t  = tb * 16 + low4;
                int byteoff = (qq * 128 + t * 2) ^ ((qq & 7) << 4);
                Plds[w][byteoff >> 1] = f2bf(s_acc[tb][r]);
            }
        __syncthreads();

        // O += P V
        #pragma unroll
        for (int kk = 0; kk < 2; ++kk) {
            bf16x8 pf = *(const bf16x8*)&Plds[w][low4 * 64 + (((kk * 4 + quad) ^ (low4 & 7)) * 8)];
            #pragma unroll
            for (int db = 0; db < 4; ++db) {
                int vrow = db * 16 + low4;
                bf16x8 vf = *(const bf16x8*)&Vlds[vrow * 64 + (((kk * 4 + quad) ^ (vrow & 7)) * 8)];
                o_acc[db] = __builtin_amdgcn_mfma_f32_16x16x32_bf16(pf, vf, o_acc[db], 0, 0, 0);
            }
        }
        __syncthreads();
    }

    float inv[4];
    #pragma unroll
    for (int r = 0; r < 4; ++r) inv[r] = 1.0f / l_r[r];
    #pragma unroll
    for (int db = 0; db < 4; ++db)
        #pragma unroll
        for (int j = 0; j < 4; ++j) {
            int s   = qt * 64 + w * 16 + quad * 4 + j;
            int col = h * DKH + db * 16 + low4;
            ao[((size_t)b * SEQ + s) * DM + col] = f2bf(o_acc[db][j] * inv[j]);
        }
}

extern "C" void kernel_launch(void* const* d_in, const int* in_sizes, int n_in,
                              void* d_out, int out_size, void* d_ws, size_t ws_size,
                              hipStream_t stream)
{
    const float* q  = (const float*)d_in[0];
    const float* k  = (const float*)d_in[1];
    const float* v  = (const float*)d_in[2];
    const float* Wq = (const float*)d_in[3];
    const float* bq = (const float*)d_in[4];
    const float* Wo = (const float*)d_in[5];
    const float* bo = (const float*)d_in[6];

    char* ws = (char*)d_ws;
    // layout (bytes): xb[0..25165824) | wqt | wot | qh | kh | vh   (total ~52 MB)
    // vt and ao alias the xb region (xb dead after the projection GEMM).
    u16* xb  = (u16*)(ws);
    u16* wqt = (u16*)(ws + 25165824);
    u16* wot = (u16*)(ws + 27262976);
    u16* qh  = (u16*)(ws + 29360128);
    u16* kh  = qh + PER_SRC;
    u16* vh  = kh + PER_SRC;
    u16* vt  = (u16*)(ws);
    u16* ao  = (u16*)(ws + 8388608);

    cast_qkv<<<dim3(2048, 3), dim3(256), 0, stream>>>(q, k, v, xb);
    wtrans<<<dim3(256, 2), dim3(256), 0, stream>>>(Wq, Wo, wqt, wot);
    gemm_bt<0><<<dim3(256, 1, 3), dim3(256), 0, stream>>>(xb, wqt, bq, (void*)qh);
    vtrans<<<dim3(32, 32), dim3(256), 0, stream>>>(vh, vt);
    attn<<<dim3(32, 32), dim3(256), 0, stream>>>(qh, kh, vt, ao);
    gemm_bt<1><<<dim3(256, 1, 1), dim3(256), 0, stream>>>(ao, wot, bo, d_out);
}

// Round 2
// 151.441 us; speedup vs baseline: 1.3679x; 1.3679x over previous
//
#include <hip/hip_runtime.h>
#include <hip/hip_bf16.h>

typedef unsigned short u16;
typedef unsigned int   u32;
typedef __attribute__((ext_vector_type(8))) short bf16x8;
typedef __attribute__((ext_vector_type(4))) float f32x4;
typedef __attribute__((ext_vector_type(16))) float f32x16;

#define SEQ     2048
#define DM      1024
#define NH      16
#define DKH     64
#define PER_SRC 4194304              // 4096*1024

__device__ __forceinline__ u16 f2bf(float f) {
    union { float f; u32 u; } c; c.f = f;
    return (u16)((c.u + 0x7fffu + ((c.u >> 16) & 1u)) >> 16);
}

__device__ __forceinline__ u32 cvt_pk_bf16(float lo, float hi) {
    u32 r;
    asm("v_cvt_pk_bf16_f32 %0, %1, %2" : "=v"(r) : "v"(lo), "v"(hi));
    return r;
}

__device__ __forceinline__ void gload_lds16(const void* g, void* l) {
    __builtin_amdgcn_global_load_lds((__attribute__((address_space(1))) void*)g,
                                     (__attribute__((address_space(3))) void*)l,
                                     16, 0, 0);
}

// ---------------- cast q/k/v fp32 -> bf16 ----------------
__global__ void cast_qkv(const float* __restrict__ q, const float* __restrict__ k,
                         const float* __restrict__ v, u16* __restrict__ xb) {
    const float* src = (blockIdx.y == 0) ? q : (blockIdx.y == 1) ? k : v;
    u16* dst = xb + (size_t)blockIdx.y * PER_SRC;
    size_t i = ((size_t)blockIdx.x * 256 + threadIdx.x) * 8;
    float4 a = *(const float4*)(src + i);
    float4 b = *(const float4*)(src + i + 4);
    bf16x8 o;
    o[0] = (short)f2bf(a.x); o[1] = (short)f2bf(a.y);
    o[2] = (short)f2bf(a.z); o[3] = (short)f2bf(a.w);
    o[4] = (short)f2bf(b.x); o[5] = (short)f2bf(b.y);
    o[6] = (short)f2bf(b.z); o[7] = (short)f2bf(b.w);
    *(bf16x8*)(dst + i) = o;
}

// ---------------- transpose-cast W [K,N] f32 -> Wt [N,K] bf16 ----------------
__global__ void wtrans(const float* __restrict__ Wq, const float* __restrict__ Wo,
                       u16* __restrict__ Wqt, u16* __restrict__ Wot) {
    const float* W = blockIdx.y ? Wo : Wq;
    u16* Wt       = blockIdx.y ? Wot : Wqt;
    int k0 = (blockIdx.x & 15) * 64;
    int n0 = (blockIdx.x >> 4) * 64;
    __shared__ __align__(16) float t[64][68];
    int tid = threadIdx.x;
    int r = tid >> 2, cs = (tid & 3) * 16;
    #pragma unroll
    for (int j = 0; j < 4; ++j) {
        float4 vv = *(const float4*)(W + (size_t)(k0 + r) * DM + n0 + cs + j * 4);
        *(float4*)&t[r][cs + j * 4] = vv;
    }
    __syncthreads();
    bf16x8 o0, o1;
    #pragma unroll
    for (int j = 0; j < 8; ++j) o0[j] = (short)f2bf(t[cs + j][r]);
    #pragma unroll
    for (int j = 0; j < 8; ++j) o1[j] = (short)f2bf(t[cs + 8 + j][r]);
    u16* dst = Wt + (size_t)(n0 + r) * DM + k0 + cs;
    *(bf16x8*)(dst)     = o0;
    *(bf16x8*)(dst + 8) = o1;
}

// ---------------- transpose vh [BH,S,64] -> vt [BH,64,S] ----------------
__global__ void vtrans(const u16* __restrict__ vh, u16* __restrict__ vt) {
    int bh = blockIdx.y, st = blockIdx.x;
    __shared__ u16 t[64][72];
    int tid = threadIdx.x;
    int r = tid >> 2, cs = (tid & 3) * 16;
    const u16* src = vh + ((size_t)bh * SEQ + st * 64 + r) * DKH + cs;
    bf16x8 v0 = *(const bf16x8*)(src);
    bf16x8 v1 = *(const bf16x8*)(src + 8);
    #pragma unroll
    for (int j = 0; j < 8; ++j) { t[r][cs + j] = (u16)v0[j]; t[r][cs + 8 + j] = (u16)v1[j]; }
    __syncthreads();
    bf16x8 o0, o1;
    #pragma unroll
    for (int j = 0; j < 8; ++j) o0[j] = (short)t[cs + j][r];
    #pragma unroll
    for (int j = 0; j < 8; ++j) o1[j] = (short)t[cs + 8 + j][r];
    u16* dst = vt + ((size_t)bh * DKH + r) * SEQ + st * 64 + cs;
    *(bf16x8*)(dst)     = o0;
    *(bf16x8*)(dst + 8) = o1;
}

// ---------------- GEMM: C = A * Bt[N=1024,K=1024]^T + bias ----------------
// MODE 0: A = flat bf16 [M,1024] (xb, +z*PER_SRC); out bf16 scattered to [B,H,S,64]
// MODE 1: A = head-major bf16 [BH,S,64] (aoh, k = h*64+d); out fp32 flat [M,1024]
template<int MODE>
__global__ __launch_bounds__(256)
void gemm_bt(const u16* __restrict__ Abase, const u16* __restrict__ Bt,
             const float* __restrict__ bias, void* __restrict__ outbase)
{
    __shared__ __align__(16) u16 Alds[128 * 64];
    __shared__ __align__(16) u16 Blds[128 * 64];

    const int tid  = threadIdx.x;
    const int wave = tid >> 6;
    const int lane = tid & 63;
    const int low4 = lane & 15;
    const int quad = lane >> 4;
    const int m0 = (blockIdx.x >> 3) * 128;
    const int n0 = (blockIdx.x & 7) * 128;
    const int wm = (wave >> 1) * 64, wn = (wave & 1) * 64;

    const u16* A = Abase + (size_t)blockIdx.z * PER_SRC;

    f32x4 acc[4][4] = {};

    for (int kt = 0; kt < DM / 64; ++kt) {
        #pragma unroll
        for (int it = 0; it < 4; ++it) {
            int seg  = it * 256 + tid;
            int row  = seg >> 3;
            int slot = seg & 7;
            int ss   = slot ^ (row & 7);   // pre-swizzled source (involution)
            const u16* srcA;
            if (MODE == 0) {
                srcA = A + (size_t)(m0 + row) * DM + kt * 64 + ss * 8;
            } else {
                int m = m0 + row;
                srcA = A + (((size_t)((m >> 11) * NH + kt)) * SEQ + (m & (SEQ - 1))) * DKH + ss * 8;
            }
            gload_lds16(srcA, &Alds[(it * 256 + wave * 64) * 8]);
            gload_lds16(Bt + (size_t)(n0 + row) * DM + kt * 64 + ss * 8,
                        &Blds[(it * 256 + wave * 64) * 8]);
        }
        __syncthreads();
        #pragma unroll
        for (int kk = 0; kk < 2; ++kk) {
            bf16x8 af[4], bfr[4];
            #pragma unroll
            for (int mi = 0; mi < 4; ++mi) {
                int row = wm + mi * 16 + low4;
                af[mi] = *(const bf16x8*)&Alds[row * 64 + (((kk * 4 + quad) ^ (row & 7)) * 8)];
            }
            #pragma unroll
            for (int ni = 0; ni < 4; ++ni) {
                int row = wn + ni * 16 + low4;
                bfr[ni] = *(const bf16x8*)&Blds[row * 64 + (((kk * 4 + quad) ^ (row & 7)) * 8)];
            }
            #pragma unroll
            for (int mi = 0; mi < 4; ++mi)
                #pragma unroll
                for (int ni = 0; ni < 4; ++ni)
                    acc[mi][ni] = __builtin_amdgcn_mfma_f32_16x16x32_bf16(
                        af[mi], bfr[ni], acc[mi][ni], 0, 0, 0);
        }
        __syncthreads();
    }

    #pragma unroll
    for (int mi = 0; mi < 4; ++mi) {
        #pragma unroll
        for (int ni = 0; ni < 4; ++ni) {
            int n = n0 + wn + ni * 16 + low4;
            float bv = bias[n];
            #pragma unroll
            for (int j = 0; j < 4; ++j) {
                int m = m0 + wm + mi * 16 + quad * 4 + j;
                float val = acc[mi][ni][j] + bv;
                if (MODE == 0) {
                    u16* dst = (u16*)outbase + (size_t)blockIdx.z * PER_SRC;
                    int b = m >> 11, s = m & (SEQ - 1);
                    int h = n >> 6, dd = n & 63;
                    dst[(size_t)(b * NH + h) * (SEQ * DKH) + (size_t)s * DKH + dd] = f2bf(val);
                } else {
                    ((float*)outbase)[(size_t)m * DM + n] = val;
                }
            }
        }
    }
}

// ---------------- flash attention, 32x32 swapped-operand structure ----------------
// Per wave: 32 q-rows. S^T = mfma(K, Q): lane owns column q = lane&31, holds the
// 32 t-values with parity (t>>2)&1 == lane>>5 (t = 32T + (r&3) + 8*(r>>2) + 4*hi).
// O^T = mfma(V^T, P^T): col q = lane&31 -> m, l, rescale, 1/l all lane-local.
__global__ __launch_bounds__(256, 2)
void attn(const u16* __restrict__ qh, const u16* __restrict__ kh,
          const u16* __restrict__ vt, u16* __restrict__ aoh)
{
    __shared__ __align__(16) u16 lds[2][8192];   // [buf][K 4096 | V 4096] double-buffered

    const int tid  = threadIdx.x;
    const int w    = tid >> 6;
    const int lane = tid & 63;
    const int l31  = lane & 31;
    const int hi   = lane >> 5;

    // XCD-chunked swizzle: each XCD gets 4 consecutive bh (all 16 q-tiles of each)
    int bid = blockIdx.x;
    int lid = (bid & 7) * 64 + (bid >> 3);
    const int qt = lid & 15;
    const int bh = lid >> 4;

    const int qbase = qt * 128 + w * 32;
    const int q_row = qbase + l31;

    // Q fragments: qf[c] holds Q[q_row][c*16 + hi*8 .. +7]
    bf16x8 qf[4];
    #pragma unroll
    for (int c = 0; c < 4; ++c)
        qf[c] = *(const bf16x8*)&qh[((size_t)bh * SEQ + q_row) * DKH + c * 16 + hi * 8];

    float m_r = -1e30f, l_r = 0.f;
    f32x16 ot[2] = {};    // O^T: col q = l31, rows d = (r&3)+8*(r>>2)+4*hi+32*dt

#define STAGE(buf, kt_)                                                                 \
    {                                                                                   \
        _Pragma("unroll")                                                               \
        for (int it = 0; it < 2; ++it) {                                                \
            int seg  = it * 256 + tid;                                                  \
            int row  = seg >> 3;                                                        \
            int slot = seg & 7;                                                         \
            int ss   = slot ^ (row & 7);                                                \
            gload_lds16(kh + ((size_t)bh * SEQ + (kt_) * 64 + row) * DKH + ss * 8,      \
                        &lds[buf][(it * 256 + w * 64) * 8]);                            \
            gload_lds16(vt + ((size_t)bh * DKH + row) * SEQ + (kt_) * 64 + ss * 8,      \
                        &lds[buf][4096 + (it * 256 + w * 64) * 8]);                     \
        }                                                                               \
    }

    STAGE(0, 0);
    __syncthreads();

    int cur = 0;
    for (int kt = 0; kt < SEQ / 64; ++kt) {
        if (kt + 1 < SEQ / 64) STAGE(cur ^ 1, kt + 1);   // prefetch next tile

        const u16* Klds = &lds[cur][0];
        const u16* Vlds = &lds[cur][4096];

        // S^T = K . Q^T
        f32x16 st[2];
        #pragma unroll
        for (int T = 0; T < 2; ++T) {
            f32x16 acc = {};
            #pragma unroll
            for (int c = 0; c < 4; ++c) {
                int row = T * 32 + l31;
                bf16x8 kf = *(const bf16x8*)&Klds[row * 64 + (((c * 2 + hi) ^ (row & 7)) * 8)];
                acc = __builtin_amdgcn_mfma_f32_32x32x16_bf16(kf, qf[c], acc, 0, 0, 0);
            }
            st[T] = acc;
        }

        // online softmax for column q (lane-local m, l)
        float mx[16];
        #pragma unroll
        for (int r = 0; r < 16; ++r) mx[r] = fmaxf(st[0][r], st[1][r]);
        #pragma unroll
        for (int s = 8; s > 0; s >>= 1)
            #pragma unroll
            for (int r = 0; r < 8; ++r) if (r < s) mx[r] = fmaxf(mx[r], mx[r + s]);
        float mloc = fmaxf(mx[0], __shfl_xor(mx[0], 32));
        float mnew = fmaxf(m_r, mloc * 0.125f);
        float fac  = __expf(m_r - mnew);
        m_r = mnew;
        float rs = 0.f;
        #pragma unroll
        for (int T = 0; T < 2; ++T)
            #pragma unroll
            for (int r = 0; r < 16; ++r) {
                float p = __expf(fmaf(st[T][r], 0.125f, -mnew));
                st[T][r] = p;
                rs += p;
            }
        rs += __shfl_xor(rs, 32);
        l_r = l_r * fac + rs;
        #pragma unroll
        for (int dt = 0; dt < 2; ++dt)
            #pragma unroll
            for (int r = 0; r < 16; ++r) ot[dt][r] *= fac;

        // pack P to bf16 pairs: pk[T][g] = (p[2g+1]<<16)|p[2g]
        u32 pk[2][8];
        #pragma unroll
        for (int T = 0; T < 2; ++T)
            #pragma unroll
            for (int g = 0; g < 8; ++g)
                pk[T][g] = cvt_pk_bf16(st[T][2 * g], st[T][2 * g + 1]);

        // P^T B-fragments per t-chunk c: t = c*16 + hi*8 + j.
        // j0..3 live in hi=0 lanes, j4..7 in hi=1 lanes; reg base = 8*(c&1)+4*hi.
        // Each lane keeps its matching half locally and swaps the other half.
        bf16x8 pfrag[4];
        #pragma unroll
        for (int c = 0; c < 4; ++c) {
            int T = c >> 1, g0 = (c & 1) * 4;
            u32 wA = pk[T][g0], wB = pk[T][g0 + 1], wC = pk[T][g0 + 2], wD = pk[T][g0 + 3];
            u32 x0 = __shfl_xor(hi ? wA : wC, 32);
            u32 x1 = __shfl_xor(hi ? wB : wD, 32);
            union { bf16x8 v; u32 u[4]; } f;
            f.u[0] = hi ? x0 : wA;
            f.u[1] = hi ? x1 : wB;
            f.u[2] = hi ? wC : x0;
            f.u[3] = hi ? wD : x1;
            pfrag[c] = f.v;
        }

        // O^T += V^T . P^T
        #pragma unroll
        for (int dt = 0; dt < 2; ++dt)
            #pragma unroll
            for (int c = 0; c < 4; ++c) {
                int row = dt * 32 + l31;
                bf16x8 vf = *(const bf16x8*)&Vlds[row * 64 + (((c * 2 + hi) ^ (row & 7)) * 8)];
                ot[dt] = __builtin_amdgcn_mfma_f32_32x32x16_bf16(vf, pfrag[c], ot[dt], 0, 0, 0);
            }

        __syncthreads();   // drains prefetch vmcnt + guards buf swap
        cur ^= 1;
    }

    // epilogue: normalize, bf16, LDS transpose (wave-private 4KB tile), coalesced store
    float inv = 1.0f / l_r;
    u16* tile = &lds[0][0] + w * 2048;
    #pragma unroll
    for (int dt = 0; dt < 2; ++dt)
        #pragma unroll
        for (int g = 0; g < 4; ++g) {
            u32 w0 = cvt_pk_bf16(ot[dt][4 * g] * inv,     ot[dt][4 * g + 1] * inv);
            u32 w1 = cvt_pk_bf16(ot[dt][4 * g + 2] * inv, ot[dt][4 * g + 3] * inv);
            int d0 = 8 * g + 4 * hi + 32 * dt;
            int byteoff = l31 * 128 + ((d0 * 2) ^ ((l31 & 7) << 4));
            uint2 pr; pr.x = w0; pr.y = w1;
            *(uint2*)((char*)tile + byteoff) = pr;
        }
    // same-wave write->read: compiler inserts lgkmcnt wait; tile is wave-private
    const size_t gbase = ((size_t)bh * SEQ + qbase) * DKH;
    #pragma unroll
    for (int p = 0; p < 4; ++p) {
        int q = p * 8 + (lane >> 3);
        int byteoff = q * 128 + (((lane & 7) * 16) ^ ((q & 7) << 4));
        bf16x8 val = *(const bf16x8*)((const char*)tile + byteoff);
        *(bf16x8*)&aoh[gbase + p * 512 + lane * 8] = val;
    }
#undef STAGE
}

extern "C" void kernel_launch(void* const* d_in, const int* in_sizes, int n_in,
                              void* d_out, int out_size, void* d_ws, size_t ws_size,
                              hipStream_t stream)
{
    const float* q  = (const float*)d_in[0];
    const float* k  = (const float*)d_in[1];
    const float* v  = (const float*)d_in[2];
    const float* Wq = (const float*)d_in[3];
    const float* bq = (const float*)d_in[4];
    const float* Wo = (const float*)d_in[5];
    const float* bo = (const float*)d_in[6];

    char* ws = (char*)d_ws;
    // layout (bytes): xb[0..24M) | wqt@24M | wot@26M | qh@28M | kh@36M | vh@44M
    // vt and aoh alias the xb region (xb dead after the projection GEMM).
    u16* xb  = (u16*)(ws);
    u16* wqt = (u16*)(ws + 25165824);
    u16* wot = (u16*)(ws + 27262976);
    u16* qh  = (u16*)(ws + 29360128);
    u16* kh  = qh + PER_SRC;
    u16* vh  = kh + PER_SRC;
    u16* vt  = (u16*)(ws);
    u16* aoh = (u16*)(ws + 8388608);

    cast_qkv<<<dim3(2048, 3), dim3(256), 0, stream>>>(q, k, v, xb);
    wtrans<<<dim3(256, 2), dim3(256), 0, stream>>>(Wq, Wo, wqt, wot);
    gemm_bt<0><<<dim3(256, 1, 3), dim3(256), 0, stream>>>(xb, wqt, bq, (void*)qh);
    vtrans<<<dim3(32, 32), dim3(256), 0, stream>>>(vh, vt);
    attn<<<dim3(512), dim3(256), 0, stream>>>(qh, kh, vt, aoh);
    gemm_bt<1><<<dim3(256), dim3(256), 0, stream>>>(aoh, wot, bo, d_out);
}

// Round 5
// 146.091 us; speedup vs baseline: 1.4180x; 1.0366x over previous
//
#include <hip/hip_runtime.h>
#include <hip/hip_bf16.h>

typedef unsigned short u16;
typedef unsigned int   u32;
typedef __attribute__((ext_vector_type(8))) short bf16x8;
typedef __attribute__((ext_vector_type(4))) float f32x4;
typedef __attribute__((ext_vector_type(16))) float f32x16;

#define SEQ     2048
#define DM      1024
#define NH      16
#define DKH     64
#define PER_SRC 4194304              // 4096*1024

__device__ __forceinline__ u16 f2bf(float f) {
    union { float f; u32 u; } c; c.f = f;
    return (u16)((c.u + 0x7fffu + ((c.u >> 16) & 1u)) >> 16);
}

__device__ __forceinline__ u32 cvt_pk_bf16(float lo, float hi) {
    u32 r;
    asm("v_cvt_pk_bf16_f32 %0, %1, %2" : "=v"(r) : "v"(lo), "v"(hi));
    return r;
}

__device__ __forceinline__ void gload_lds16(const void* g, void* l) {
    __builtin_amdgcn_global_load_lds((__attribute__((address_space(1))) void*)g,
                                     (__attribute__((address_space(3))) void*)l,
                                     16, 0, 0);
}

// ---------------- cast q/k/v fp32 -> bf16 ----------------
__global__ void cast_qkv(const float* __restrict__ q, const float* __restrict__ k,
                         const float* __restrict__ v, u16* __restrict__ xb) {
    const float* src = (blockIdx.y == 0) ? q : (blockIdx.y == 1) ? k : v;
    u16* dst = xb + (size_t)blockIdx.y * PER_SRC;
    size_t i = ((size_t)blockIdx.x * 256 + threadIdx.x) * 8;
    float4 a = *(const float4*)(src + i);
    float4 b = *(const float4*)(src + i + 4);
    bf16x8 o;
    o[0] = (short)f2bf(a.x); o[1] = (short)f2bf(a.y);
    o[2] = (short)f2bf(a.z); o[3] = (short)f2bf(a.w);
    o[4] = (short)f2bf(b.x); o[5] = (short)f2bf(b.y);
    o[6] = (short)f2bf(b.z); o[7] = (short)f2bf(b.w);
    *(bf16x8*)(dst + i) = o;
}

// ---------------- transpose-cast W [K,N] f32 -> Wt [N,K] bf16 ----------------
__global__ void wtrans(const float* __restrict__ Wq, const float* __restrict__ Wo,
                       u16* __restrict__ Wqt, u16* __restrict__ Wot) {
    const float* W = blockIdx.y ? Wo : Wq;
    u16* Wt       = blockIdx.y ? Wot : Wqt;
    int k0 = (blockIdx.x & 15) * 64;
    int n0 = (blockIdx.x >> 4) * 64;
    __shared__ __align__(16) float t[64][68];
    int tid = threadIdx.x;
    int r = tid >> 2, cs = (tid & 3) * 16;
    #pragma unroll
    for (int j = 0; j < 4; ++j) {
        float4 vv = *(const float4*)(W + (size_t)(k0 + r) * DM + n0 + cs + j * 4);
        *(float4*)&t[r][cs + j * 4] = vv;
    }
    __syncthreads();
    bf16x8 o0, o1;
    #pragma unroll
    for (int j = 0; j < 8; ++j) o0[j] = (short)f2bf(t[cs + j][r]);
    #pragma unroll
    for (int j = 0; j < 8; ++j) o1[j] = (short)f2bf(t[cs + 8 + j][r]);
    u16* dst = Wt + (size_t)(n0 + r) * DM + k0 + cs;
    *(bf16x8*)(dst)     = o0;
    *(bf16x8*)(dst + 8) = o1;
}

// ---------------- transpose vh [BH,S,64] -> vt [BH,64,S] ----------------
__global__ void vtrans(const u16* __restrict__ vh, u16* __restrict__ vt) {
    int bh = blockIdx.y, st = blockIdx.x;
    __shared__ u16 t[64][72];
    int tid = threadIdx.x;
    int r = tid >> 2, cs = (tid & 3) * 16;
    const u16* src = vh + ((size_t)bh * SEQ + st * 64 + r) * DKH + cs;
    bf16x8 v0 = *(const bf16x8*)(src);
    bf16x8 v1 = *(const bf16x8*)(src + 8);
    #pragma unroll
    for (int j = 0; j < 8; ++j) { t[r][cs + j] = (u16)v0[j]; t[r][cs + 8 + j] = (u16)v1[j]; }
    __syncthreads();
    bf16x8 o0, o1;
    #pragma unroll
    for (int j = 0; j < 8; ++j) o0[j] = (short)t[cs + j][r];
    #pragma unroll
    for (int j = 0; j < 8; ++j) o1[j] = (short)t[cs + 8 + j][r];
    u16* dst = vt + ((size_t)bh * DKH + r) * SEQ + st * 64 + cs;
    *(bf16x8*)(dst)     = o0;
    *(bf16x8*)(dst + 8) = o1;
}

// ---------------- GEMM: C = A * Bt[N=1024,K=1024]^T + bias ----------------
// MODE 0: A = flat bf16 [M,1024] (xb, +z*PER_SRC); out bf16 scattered to [B,H,S,64]
// MODE 1: A = head-major bf16 [BH,S,64] (aoh, k = h*64+d); out fp32 flat [M,1024]
template<int MODE>
__global__ __launch_bounds__(256)
void gemm_bt(const u16* __restrict__ Abase, const u16* __restrict__ Bt,
             const float* __restrict__ bias, void* __restrict__ outbase)
{
    __shared__ __align__(16) u16 Alds[128 * 64];
    __shared__ __align__(16) u16 Blds[128 * 64];

    const int tid  = threadIdx.x;
    const int wave = tid >> 6;
    const int lane = tid & 63;
    const int low4 = lane & 15;
    const int quad = lane >> 4;
    const int m0 = (blockIdx.x >> 3) * 128;
    const int n0 = (blockIdx.x & 7) * 128;
    const int wm = (wave >> 1) * 64, wn = (wave & 1) * 64;

    const u16* A = Abase + (size_t)blockIdx.z * PER_SRC;

    f32x4 acc[4][4] = {};

    for (int kt = 0; kt < DM / 64; ++kt) {
        #pragma unroll
        for (int it = 0; it < 4; ++it) {
            int seg  = it * 256 + tid;
            int row  = seg >> 3;
            int slot = seg & 7;
            int ss   = slot ^ (row & 7);   // pre-swizzled source (involution)
            const u16* srcA;
            if (MODE == 0) {
                srcA = A + (size_t)(m0 + row) * DM + kt * 64 + ss * 8;
            } else {
                int m = m0 + row;
                srcA = A + (((size_t)((m >> 11) * NH + kt)) * SEQ + (m & (SEQ - 1))) * DKH + ss * 8;
            }
            gload_lds16(srcA, &Alds[(it * 256 + wave * 64) * 8]);
            gload_lds16(Bt + (size_t)(n0 + row) * DM + kt * 64 + ss * 8,
                        &Blds[(it * 256 + wave * 64) * 8]);
        }
        __syncthreads();
        #pragma unroll
        for (int kk = 0; kk < 2; ++kk) {
            bf16x8 af[4], bfr[4];
            #pragma unroll
            for (int mi = 0; mi < 4; ++mi) {
                int row = wm + mi * 16 + low4;
                af[mi] = *(const bf16x8*)&Alds[row * 64 + (((kk * 4 + quad) ^ (row & 7)) * 8)];
            }
            #pragma unroll
            for (int ni = 0; ni < 4; ++ni) {
                int row = wn + ni * 16 + low4;
                bfr[ni] = *(const bf16x8*)&Blds[row * 64 + (((kk * 4 + quad) ^ (row & 7)) * 8)];
            }
            #pragma unroll
            for (int mi = 0; mi < 4; ++mi)
                #pragma unroll
                for (int ni = 0; ni < 4; ++ni)
                    acc[mi][ni] = __builtin_amdgcn_mfma_f32_16x16x32_bf16(
                        af[mi], bfr[ni], acc[mi][ni], 0, 0, 0);
        }
        __syncthreads();
    }

    #pragma unroll
    for (int mi = 0; mi < 4; ++mi) {
        #pragma unroll
        for (int ni = 0; ni < 4; ++ni) {
            int n = n0 + wn + ni * 16 + low4;
            float bv = bias[n];
            #pragma unroll
            for (int j = 0; j < 4; ++j) {
                int m = m0 + wm + mi * 16 + quad * 4 + j;
                float val = acc[mi][ni][j] + bv;
                if (MODE == 0) {
                    u16* dst = (u16*)outbase + (size_t)blockIdx.z * PER_SRC;
                    int b = m >> 11, s = m & (SEQ - 1);
                    int h = n >> 6, dd = n & 63;
                    dst[(size_t)(b * NH + h) * (SEQ * DKH) + (size_t)s * DKH + dd] = f2bf(val);
                } else {
                    ((float*)outbase)[(size_t)m * DM + n] = val;
                }
            }
        }
    }
}

// ---------------- flash attention, 32x32 swapped-operand structure ----------------
// Per wave: 32 q-rows. S^T = mfma(K, Q): lane owns column q = lane&31, holds 32
// t-values with bit2(t) == lane>>5 (t = 32T + (r&3) + 8*(r>>2) + 4*hi).
// O^T = mfma(V^T, P^T): col q = lane&31 -> m, l, rescale, 1/l all lane-local.
// Softmax runs in log2 domain (v_exp_f32 IS exp2); SC = 0.125*log2(e).
// Cross-half exchange uses __shfl_xor(,32) ONLY (HW-verified in round 2).
__global__ __launch_bounds__(256, 2)
void attn(const u16* __restrict__ qh, const u16* __restrict__ kh,
          const u16* __restrict__ vt, u16* __restrict__ aoh)
{
    __shared__ __align__(16) u16 lds[2][8192];   // [buf][K 4096 | V 4096] double-buffered

    const int tid  = threadIdx.x;
    const int w    = tid >> 6;
    const int lane = tid & 63;
    const int l31  = lane & 31;
    const int hi   = lane >> 5;

    // XCD-chunked swizzle: each XCD gets 4 consecutive bh (all 16 q-tiles of each)
    int bid = blockIdx.x;
    int lid = (bid & 7) * 64 + (bid >> 3);
    const int qt = lid & 15;
    const int bh = lid >> 4;

    const int qbase = qt * 128 + w * 32;
    const int q_row = qbase + l31;

    const float SC = 0.18033688f;   // 0.125 * log2(e)

    // Q fragments: qf[c] holds Q[q_row][c*16 + hi*8 .. +7]
    bf16x8 qf[4];
    #pragma unroll
    for (int c = 0; c < 4; ++c)
        qf[c] = *(const bf16x8*)&qh[((size_t)bh * SEQ + q_row) * DKH + c * 16 + hi * 8];

    float m_r = -1e30f, l_r = 0.f;
    f32x16 ot[2] = {};    // O^T: col q = l31, rows d = (r&3)+8*(r>>2)+4*hi+32*dt

#define STAGE(buf, kt_)                                                                 \
    {                                                                                   \
        _Pragma("unroll")                                                               \
        for (int it = 0; it < 2; ++it) {                                                \
            int seg  = it * 256 + tid;                                                  \
            int row  = seg >> 3;                                                        \
            int slot = seg & 7;                                                         \
            int ss   = slot ^ (row & 7);                                                \
            gload_lds16(kh + ((size_t)bh * SEQ + (kt_) * 64 + row) * DKH + ss * 8,      \
                        &lds[buf][(it * 256 + w * 64) * 8]);                            \
            gload_lds16(vt + ((size_t)bh * DKH + row) * SEQ + (kt_) * 64 + ss * 8,      \
                        &lds[buf][4096 + (it * 256 + w * 64) * 8]);                     \
        }                                                                               \
    }

    STAGE(0, 0);
    __syncthreads();

    int cur = 0;
    for (int kt = 0; kt < SEQ / 64; ++kt) {
        if (kt + 1 < SEQ / 64) STAGE(cur ^ 1, kt + 1);   // prefetch next tile

        const u16* Klds = &lds[cur][0];
        const u16* Vlds = &lds[cur][4096];

        // S^T = K . Q^T
        f32x16 st[2];
        #pragma unroll
        for (int T = 0; T < 2; ++T) {
            f32x16 acc = {};
            __builtin_amdgcn_s_setprio(1);
            #pragma unroll
            for (int c = 0; c < 4; ++c) {
                int row = T * 32 + l31;
                bf16x8 kf = *(const bf16x8*)&Klds[row * 64 + (((c * 2 + hi) ^ (row & 7)) * 8)];
                acc = __builtin_amdgcn_mfma_f32_32x32x16_bf16(kf, qf[c], acc, 0, 0, 0);
            }
            __builtin_amdgcn_s_setprio(0);
            st[T] = acc;
        }

        // ---- online softmax for column q (lane-local m, l; log2 domain) ----
        float mx[8];
        #pragma unroll
        for (int r = 0; r < 8; ++r)
            mx[r] = fmaxf(fmaxf(st[0][r], st[0][r + 8]),
                          fmaxf(st[1][r], st[1][r + 8]));
        float t0 = fmaxf(fmaxf(mx[0], mx[1]), mx[2]);
        float t1 = fmaxf(fmaxf(mx[3], mx[4]), mx[5]);
        float t2 = fmaxf(mx[6], mx[7]);
        float lmax = fmaxf(fmaxf(t0, t1), t2);
        float mloc = fmaxf(lmax, __shfl_xor(lmax, 32)) * SC;

        float mnew = fmaxf(m_r, mloc);
        if (!__all(mloc <= m_r + 11.5f)) {        // defer-max: rescale only on real growth
            float fac = __builtin_amdgcn_exp2f(m_r - mnew);
            m_r = mnew;
            l_r *= fac;
            #pragma unroll
            for (int dt = 0; dt < 2; ++dt)
                #pragma unroll
                for (int r = 0; r < 16; ++r) ot[dt][r] *= fac;
        }

        float nm = -m_r;
        float rs0 = 0.f, rs1 = 0.f, rs2 = 0.f, rs3 = 0.f;
        #pragma unroll
        for (int T = 0; T < 2; ++T)
            #pragma unroll
            for (int r = 0; r < 16; r += 4) {
                float p0 = __builtin_amdgcn_exp2f(fmaf(st[T][r],     SC, nm));
                float p1 = __builtin_amdgcn_exp2f(fmaf(st[T][r + 1], SC, nm));
                float p2 = __builtin_amdgcn_exp2f(fmaf(st[T][r + 2], SC, nm));
                float p3 = __builtin_amdgcn_exp2f(fmaf(st[T][r + 3], SC, nm));
                st[T][r] = p0; st[T][r + 1] = p1; st[T][r + 2] = p2; st[T][r + 3] = p3;
                rs0 += p0; rs1 += p1; rs2 += p2; rs3 += p3;
            }
        float rsum = (rs0 + rs1) + (rs2 + rs3);
        l_r += rsum + __shfl_xor(rsum, 32);

        // pack P to bf16 pairs: pk[T][g] = (p[2g+1]<<16)|p[2g]
        u32 pk[2][8];
        #pragma unroll
        for (int T = 0; T < 2; ++T)
            #pragma unroll
            for (int g = 0; g < 8; ++g)
                pk[T][g] = cvt_pk_bf16(st[T][2 * g], st[T][2 * g + 1]);

        // P^T B-fragments per t-chunk c: t = c*16 + hi*8 + j.
        // j0..3 live in hi=0 lanes, j4..7 in hi=1 lanes; exchange via shfl_xor(32)
        // (each lane sends its partner-needed word, receives its missing word).
        bf16x8 pfrag[4];
        #pragma unroll
        for (int c = 0; c < 4; ++c) {
            int T = c >> 1, g0 = (c & 1) * 4;
            u32 wA = pk[T][g0], wB = pk[T][g0 + 1], wC = pk[T][g0 + 2], wD = pk[T][g0 + 3];
            u32 x0 = __shfl_xor(hi ? wA : wC, 32);
            u32 x1 = __shfl_xor(hi ? wB : wD, 32);
            union { bf16x8 v; u32 u[4]; } f;
            f.u[0] = hi ? x0 : wA;
            f.u[1] = hi ? x1 : wB;
            f.u[2] = hi ? wC : x0;
            f.u[3] = hi ? wD : x1;
            pfrag[c] = f.v;
        }

        // O^T += V^T . P^T
        __builtin_amdgcn_s_setprio(1);
        #pragma unroll
        for (int dt = 0; dt < 2; ++dt)
            #pragma unroll
            for (int c = 0; c < 4; ++c) {
                int row = dt * 32 + l31;
                bf16x8 vf = *(const bf16x8*)&Vlds[row * 64 + (((c * 2 + hi) ^ (row & 7)) * 8)];
                ot[dt] = __builtin_amdgcn_mfma_f32_32x32x16_bf16(vf, pfrag[c], ot[dt], 0, 0, 0);
            }
        __builtin_amdgcn_s_setprio(0);

        __syncthreads();   // drains prefetch vmcnt + guards buf swap
        cur ^= 1;
    }

    // epilogue: normalize, bf16, LDS transpose (wave-private 4KB tile), coalesced store
    float inv = 1.0f / l_r;
    u16* tile = &lds[0][0] + w * 2048;
    #pragma unroll
    for (int dt = 0; dt < 2; ++dt)
        #pragma unroll
        for (int g = 0; g < 4; ++g) {
            u32 w0 = cvt_pk_bf16(ot[dt][4 * g] * inv,     ot[dt][4 * g + 1] * inv);
            u32 w1 = cvt_pk_bf16(ot[dt][4 * g + 2] * inv, ot[dt][4 * g + 3] * inv);
            int d0 = 8 * g + 4 * hi + 32 * dt;
            int byteoff = l31 * 128 + ((d0 * 2) ^ ((l31 & 7) << 4));
            uint2 pr; pr.x = w0; pr.y = w1;
            *(uint2*)((char*)tile + byteoff) = pr;
        }
    // same-wave write->read: compiler inserts lgkmcnt wait; tile is wave-private
    const size_t gbase = ((size_t)bh * SEQ + qbase) * DKH;
    #pragma unroll
    for (int p = 0; p < 4; ++p) {
        int q = p * 8 + (lane >> 3);
        int byteoff = q * 128 + (((lane & 7) * 16) ^ ((q & 7) << 4));
        bf16x8 val = *(const bf16x8*)((const char*)tile + byteoff);
        *(bf16x8*)&aoh[gbase + p * 512 + lane * 8] = val;
    }
#undef STAGE
}

extern "C" void kernel_launch(void* const* d_in, const int* in_sizes, int n_in,
                              void* d_out, int out_size, void* d_ws, size_t ws_size,
                              hipStream_t stream)
{
    const float* q  = (const float*)d_in[0];
    const float* k  = (const float*)d_in[1];
    const float* v  = (const float*)d_in[2];
    const float* Wq = (const float*)d_in[3];
    const float* bq = (const float*)d_in[4];
    const float* Wo = (const float*)d_in[5];
    const float* bo = (const float*)d_in[6];

    char* ws = (char*)d_ws;
    // layout (bytes): xb[0..24M) | wqt@24M | wot@26M | qh@28M | kh@36M | vh@44M
    // vt and aoh alias the xb region (xb dead after the projection GEMM).
    u16* xb  = (u16*)(ws);
    u16* wqt = (u16*)(ws + 25165824);
    u16* wot = (u16*)(ws + 27262976);
    u16* qh  = (u16*)(ws + 29360128);
    u16* kh  = qh + PER_SRC;
    u16* vh  = kh + PER_SRC;
    u16* vt  = (u16*)(ws);
    u16* aoh = (u16*)(ws + 8388608);

    cast_qkv<<<dim3(2048, 3), dim3(256), 0, stream>>>(q, k, v, xb);
    wtrans<<<dim3(256, 2), dim3(256), 0, stream>>>(Wq, Wo, wqt, wot);
    gemm_bt<0><<<dim3(256, 1, 3), dim3(256), 0, stream>>>(xb, wqt, bq, (void*)qh);
    vtrans<<<dim3(32, 32), dim3(256), 0, stream>>>(vh, vt);
    attn<<<dim3(512), dim3(256), 0, stream>>>(qh, kh, vt, aoh);
    gemm_bt<1><<<dim3(256), dim3(256), 0, stream>>>(aoh, wot, bo, d_out);
}

// Round 6
// 144.604 us; speedup vs baseline: 1.4326x; 1.0103x over previous
//
#include <hip/hip_runtime.h>
#include <hip/hip_bf16.h>

typedef unsigned short u16;
typedef unsigned int   u32;
typedef __attribute__((ext_vector_type(8))) short bf16x8;
typedef __attribute__((ext_vector_type(4))) float f32x4;
typedef __attribute__((ext_vector_type(16))) float f32x16;

#define SEQ     2048
#define DM      1024
#define NH      16
#define DKH     64
#define PER_SRC 4194304              // 4096*1024

__device__ __forceinline__ u16 f2bf(float f) {
    union { float f; u32 u; } c; c.f = f;
    return (u16)((c.u + 0x7fffu + ((c.u >> 16) & 1u)) >> 16);
}

__device__ __forceinline__ u32 cvt_pk_bf16(float lo, float hi) {
    u32 r;
    asm("v_cvt_pk_bf16_f32 %0, %1, %2" : "=v"(r) : "v"(lo), "v"(hi));
    return r;
}

__device__ __forceinline__ void gload_lds16(const void* g, void* l) {
    __builtin_amdgcn_global_load_lds((__attribute__((address_space(1))) void*)g,
                                     (__attribute__((address_space(3))) void*)l,
                                     16, 0, 0);
}

// ---------------- cast q/k/v fp32 -> bf16 ----------------
__global__ void cast_qkv(const float* __restrict__ q, const float* __restrict__ k,
                         const float* __restrict__ v, u16* __restrict__ xb) {
    const float* src = (blockIdx.y == 0) ? q : (blockIdx.y == 1) ? k : v;
    u16* dst = xb + (size_t)blockIdx.y * PER_SRC;
    size_t i = ((size_t)blockIdx.x * 256 + threadIdx.x) * 8;
    float4 a = *(const float4*)(src + i);
    float4 b = *(const float4*)(src + i + 4);
    bf16x8 o;
    o[0] = (short)f2bf(a.x); o[1] = (short)f2bf(a.y);
    o[2] = (short)f2bf(a.z); o[3] = (short)f2bf(a.w);
    o[4] = (short)f2bf(b.x); o[5] = (short)f2bf(b.y);
    o[6] = (short)f2bf(b.z); o[7] = (short)f2bf(b.w);
    *(bf16x8*)(dst + i) = o;
}

// ---------------- transpose-cast W [K,N] f32 -> Wt [N,K] bf16 ----------------
__global__ void wtrans(const float* __restrict__ Wq, const float* __restrict__ Wo,
                       u16* __restrict__ Wqt, u16* __restrict__ Wot) {
    const float* W = blockIdx.y ? Wo : Wq;
    u16* Wt       = blockIdx.y ? Wot : Wqt;
    int k0 = (blockIdx.x & 15) * 64;
    int n0 = (blockIdx.x >> 4) * 64;
    __shared__ __align__(16) float t[64][68];
    int tid = threadIdx.x;
    int r = tid >> 2, cs = (tid & 3) * 16;
    #pragma unroll
    for (int j = 0; j < 4; ++j) {
        float4 vv = *(const float4*)(W + (size_t)(k0 + r) * DM + n0 + cs + j * 4);
        *(float4*)&t[r][cs + j * 4] = vv;
    }
    __syncthreads();
    bf16x8 o0, o1;
    #pragma unroll
    for (int j = 0; j < 8; ++j) o0[j] = (short)f2bf(t[cs + j][r]);
    #pragma unroll
    for (int j = 0; j < 8; ++j) o1[j] = (short)f2bf(t[cs + 8 + j][r]);
    u16* dst = Wt + (size_t)(n0 + r) * DM + k0 + cs;
    *(bf16x8*)(dst)     = o0;
    *(bf16x8*)(dst + 8) = o1;
}

// ---------------- transpose vh [BH,S,64] -> vt [BH,64,S] ----------------
__global__ void vtrans(const u16* __restrict__ vh, u16* __restrict__ vt) {
    int bh = blockIdx.y, st = blockIdx.x;
    __shared__ u16 t[64][72];
    int tid = threadIdx.x;
    int r = tid >> 2, cs = (tid & 3) * 16;
    const u16* src = vh + ((size_t)bh * SEQ + st * 64 + r) * DKH + cs;
    bf16x8 v0 = *(const bf16x8*)(src);
    bf16x8 v1 = *(const bf16x8*)(src + 8);
    #pragma unroll
    for (int j = 0; j < 8; ++j) { t[r][cs + j] = (u16)v0[j]; t[r][cs + 8 + j] = (u16)v1[j]; }
    __syncthreads();
    bf16x8 o0, o1;
    #pragma unroll
    for (int j = 0; j < 8; ++j) o0[j] = (short)t[cs + j][r];
    #pragma unroll
    for (int j = 0; j < 8; ++j) o1[j] = (short)t[cs + 8 + j][r];
    u16* dst = vt + ((size_t)bh * DKH + r) * SEQ + st * 64 + cs;
    *(bf16x8*)(dst)     = o0;
    *(bf16x8*)(dst + 8) = o1;
}

// ---------------- GEMM: C = A * Bt[N=1024,K=1024]^T + bias ----------------
// MODE 0: A = flat bf16 [M,1024] (xb, +z*PER_SRC); out bf16 scattered to [B,H,S,64]
// MODE 1: A = head-major bf16 [BH,S,64] (aoh, k = h*64+d); out fp32 flat [M,1024]
template<int MODE>
__global__ __launch_bounds__(256)
void gemm_bt(const u16* __restrict__ Abase, const u16* __restrict__ Bt,
             const float* __restrict__ bias, void* __restrict__ outbase)
{
    __shared__ __align__(16) u16 Alds[128 * 64];
    __shared__ __align__(16) u16 Blds[128 * 64];

    const int tid  = threadIdx.x;
    const int wave = tid >> 6;
    const int lane = tid & 63;
    const int low4 = lane & 15;
    const int quad = lane >> 4;
    const int m0 = (blockIdx.x >> 3) * 128;
    const int n0 = (blockIdx.x & 7) * 128;
    const int wm = (wave >> 1) * 64, wn = (wave & 1) * 64;

    const u16* A = Abase + (size_t)blockIdx.z * PER_SRC;

    f32x4 acc[4][4] = {};

    for (int kt = 0; kt < DM / 64; ++kt) {
        #pragma unroll
        for (int it = 0; it < 4; ++it) {
            int seg  = it * 256 + tid;
            int row  = seg >> 3;
            int slot = seg & 7;
            int ss   = slot ^ (row & 7);   // pre-swizzled source (involution)
            const u16* srcA;
            if (MODE == 0) {
                srcA = A + (size_t)(m0 + row) * DM + kt * 64 + ss * 8;
            } else {
                int m = m0 + row;
                srcA = A + (((size_t)((m >> 11) * NH + kt)) * SEQ + (m & (SEQ - 1))) * DKH + ss * 8;
            }
            gload_lds16(srcA, &Alds[(it * 256 + wave * 64) * 8]);
            gload_lds16(Bt + (size_t)(n0 + row) * DM + kt * 64 + ss * 8,
                        &Blds[(it * 256 + wave * 64) * 8]);
        }
        __syncthreads();
        #pragma unroll
        for (int kk = 0; kk < 2; ++kk) {
            bf16x8 af[4], bfr[4];
            #pragma unroll
            for (int mi = 0; mi < 4; ++mi) {
                int row = wm + mi * 16 + low4;
                af[mi] = *(const bf16x8*)&Alds[row * 64 + (((kk * 4 + quad) ^ (row & 7)) * 8)];
            }
            #pragma unroll
            for (int ni = 0; ni < 4; ++ni) {
                int row = wn + ni * 16 + low4;
                bfr[ni] = *(const bf16x8*)&Blds[row * 64 + (((kk * 4 + quad) ^ (row & 7)) * 8)];
            }
            #pragma unroll
            for (int mi = 0; mi < 4; ++mi)
                #pragma unroll
                for (int ni = 0; ni < 4; ++ni)
                    acc[mi][ni] = __builtin_amdgcn_mfma_f32_16x16x32_bf16(
                        af[mi], bfr[ni], acc[mi][ni], 0, 0, 0);
        }
        __syncthreads();
    }

    #pragma unroll
    for (int mi = 0; mi < 4; ++mi) {
        #pragma unroll
        for (int ni = 0; ni < 4; ++ni) {
            int n = n0 + wn + ni * 16 + low4;
            float bv = bias[n];
            #pragma unroll
            for (int j = 0; j < 4; ++j) {
                int m = m0 + wm + mi * 16 + quad * 4 + j;
                float val = acc[mi][ni][j] + bv;
                if (MODE == 0) {
                    u16* dst = (u16*)outbase + (size_t)blockIdx.z * PER_SRC;
                    int b = m >> 11, s = m & (SEQ - 1);
                    int h = n >> 6, dd = n & 63;
                    dst[(size_t)(b * NH + h) * (SEQ * DKH) + (size_t)s * DKH + dd] = f2bf(val);
                } else {
                    ((float*)outbase)[(size_t)m * DM + n] = val;
                }
            }
        }
    }
}

// ---------------- flash attention, 32x32 swapped-operand structure ----------------
// Per wave: 32 q-rows. S^T = mfma(K, Q): lane owns column q = lane&31, holds 32
// t-values at t = 32T + (r&3) + 8*(r>>2) + 4*hi.
// O^T = mfma(V^T_perm, P^T_perm): PV uses the k-order permutation
//   t(c,hi,j) = c*16 + hi*4 + (j&3) + (j>>2)*8
// so B-reg j = st[c>>1][(c&1)*8 + (j>>2)*4 + (j&3)] is LANE-LOCAL (no exchange);
// the A-operand (V^T) absorbs the permutation via two b64 reads per (dt,c).
// Softmax in log2 domain (v_exp_f32 IS exp2); SC = 0.125*log2(e).
__global__ __launch_bounds__(256, 2)
void attn(const u16* __restrict__ qh, const u16* __restrict__ kh,
          const u16* __restrict__ vt, u16* __restrict__ aoh)
{
    __shared__ __align__(16) u16 lds[2][8192];   // [buf][K 4096 | V 4096] double-buffered

    const int tid  = threadIdx.x;
    const int w    = tid >> 6;
    const int lane = tid & 63;
    const int l31  = lane & 31;
    const int hi   = lane >> 5;

    // XCD-chunked swizzle: each XCD gets 4 consecutive bh (all 16 q-tiles of each)
    int bid = blockIdx.x;
    int lid = (bid & 7) * 64 + (bid >> 3);
    const int qt = lid & 15;
    const int bh = lid >> 4;

    const int qbase = qt * 128 + w * 32;
    const int q_row = qbase + l31;

    const float SC = 0.18033688f;   // 0.125 * log2(e)

    // Q fragments: qf[c] holds Q[q_row][c*16 + hi*8 .. +7]
    bf16x8 qf[4];
    #pragma unroll
    for (int c = 0; c < 4; ++c)
        qf[c] = *(const bf16x8*)&qh[((size_t)bh * SEQ + q_row) * DKH + c * 16 + hi * 8];

    float m_r = -1e30f, l_r = 0.f;
    f32x16 ot[2] = {};    // O^T: col q = l31, rows d = (r&3)+8*(r>>2)+4*hi+32*dt

#define STAGE(buf, kt_)                                                                 \
    {                                                                                   \
        _Pragma("unroll")                                                               \
        for (int it = 0; it < 2; ++it) {                                                \
            int seg  = it * 256 + tid;                                                  \
            int row  = seg >> 3;                                                        \
            int slot = seg & 7;                                                         \
            int ss   = slot ^ (row & 7);                                                \
            gload_lds16(kh + ((size_t)bh * SEQ + (kt_) * 64 + row) * DKH + ss * 8,      \
                        &lds[buf][(it * 256 + w * 64) * 8]);                            \
            gload_lds16(vt + ((size_t)bh * DKH + row) * SEQ + (kt_) * 64 + ss * 8,      \
                        &lds[buf][4096 + (it * 256 + w * 64) * 8]);                     \
        }                                                                               \
    }

    STAGE(0, 0);
    __syncthreads();

    int cur = 0;
    for (int kt = 0; kt < SEQ / 64; ++kt) {
        if (kt + 1 < SEQ / 64) STAGE(cur ^ 1, kt + 1);   // prefetch next tile

        const u16* Klds = &lds[cur][0];
        const u16* Vlds = &lds[cur][4096];

        // S^T = K . Q^T
        f32x16 st[2];
        #pragma unroll
        for (int T = 0; T < 2; ++T) {
            f32x16 acc = {};
            __builtin_amdgcn_s_setprio(1);
            #pragma unroll
            for (int c = 0; c < 4; ++c) {
                int row = T * 32 + l31;
                bf16x8 kf = *(const bf16x8*)&Klds[row * 64 + (((c * 2 + hi) ^ (row & 7)) * 8)];
                acc = __builtin_amdgcn_mfma_f32_32x32x16_bf16(kf, qf[c], acc, 0, 0, 0);
            }
            __builtin_amdgcn_s_setprio(0);
            st[T] = acc;
        }

        // ---- online softmax for column q (lane-local m, l; log2 domain) ----
        float mx[8];
        #pragma unroll
        for (int r = 0; r < 8; ++r)
            mx[r] = fmaxf(fmaxf(st[0][r], st[0][r + 8]),
                          fmaxf(st[1][r], st[1][r + 8]));
        float t0 = fmaxf(fmaxf(mx[0], mx[1]), mx[2]);
        float t1 = fmaxf(fmaxf(mx[3], mx[4]), mx[5]);
        float t2 = fmaxf(mx[6], mx[7]);
        float lmax = fmaxf(fmaxf(t0, t1), t2);
        float mloc = fmaxf(lmax, __shfl_xor(lmax, 32)) * SC;

        float mnew = fmaxf(m_r, mloc);
        if (!__all(mloc <= m_r + 11.5f)) {        // defer-max: rescale only on real growth
            float fac = __builtin_amdgcn_exp2f(m_r - mnew);
            m_r = mnew;
            l_r *= fac;
            #pragma unroll
            for (int dt = 0; dt < 2; ++dt)
                #pragma unroll
                for (int r = 0; r < 16; ++r) ot[dt][r] *= fac;
        }

        float nm = -m_r;
        float rs0 = 0.f, rs1 = 0.f, rs2 = 0.f, rs3 = 0.f;
        #pragma unroll
        for (int T = 0; T < 2; ++T)
            #pragma unroll
            for (int r = 0; r < 16; r += 4) {
                float p0 = __builtin_amdgcn_exp2f(fmaf(st[T][r],     SC, nm));
                float p1 = __builtin_amdgcn_exp2f(fmaf(st[T][r + 1], SC, nm));
                float p2 = __builtin_amdgcn_exp2f(fmaf(st[T][r + 2], SC, nm));
                float p3 = __builtin_amdgcn_exp2f(fmaf(st[T][r + 3], SC, nm));
                st[T][r] = p0; st[T][r + 1] = p1; st[T][r + 2] = p2; st[T][r + 3] = p3;
                rs0 += p0; rs1 += p1; rs2 += p2; rs3 += p3;
            }
        float rsum = (rs0 + rs1) + (rs2 + rs3);
        l_r += rsum + __shfl_xor(rsum, 32);

        // pack P to bf16 pairs: pk[T][g] = (p[2g+1]<<16)|p[2g].
        // With the k-permutation, pfrag[c] words are pk[c>>1][(c&1)*4 + 0..3]
        // directly (reg j holds st[(c&1)*8 + (j>>2)*4 + (j&3)]) — all lane-local.
        u32 pk[2][8];
        #pragma unroll
        for (int T = 0; T < 2; ++T)
            #pragma unroll
            for (int g = 0; g < 8; ++g)
                pk[T][g] = cvt_pk_bf16(st[T][2 * g], st[T][2 * g + 1]);

        // O^T += V^T_perm . P^T_perm; A-reg j holds V^T[d][t(c,hi,j)]:
        // chunk j=0..3 at swizzled slot (c*2)^(row&7), sub-offset hi*8 bytes;
        // chunk j=4..7 at swizzled slot (c*2+1)^(row&7), sub-offset hi*8 bytes.
        __builtin_amdgcn_s_setprio(1);
        #pragma unroll
        for (int dt = 0; dt < 2; ++dt)
            #pragma unroll
            for (int c = 0; c < 4; ++c) {
                int row = dt * 32 + l31;
                const char* vrow = (const char*)&Vlds[row * 64];
                union { bf16x8 v; uint2 d[2]; } vf;
                vf.d[0] = *(const uint2*)(vrow + (((c * 2)     ^ (row & 7)) * 16) + hi * 8);
                vf.d[1] = *(const uint2*)(vrow + (((c * 2 + 1) ^ (row & 7)) * 16) + hi * 8);
                union { bf16x8 v; u32 u[4]; } pf;
                int T = c >> 1, g0 = (c & 1) * 4;
                pf.u[0] = pk[T][g0];     pf.u[1] = pk[T][g0 + 1];
                pf.u[2] = pk[T][g0 + 2]; pf.u[3] = pk[T][g0 + 3];
                ot[dt] = __builtin_amdgcn_mfma_f32_32x32x16_bf16(vf.v, pf.v, ot[dt], 0, 0, 0);
            }
        __builtin_amdgcn_s_setprio(0);

        __syncthreads();   // drains prefetch vmcnt + guards buf swap
        cur ^= 1;
    }

    // epilogue: normalize, bf16, LDS transpose (wave-private 4KB tile), coalesced store
    float inv = 1.0f / l_r;
    u16* tile = &lds[0][0] + w * 2048;
    #pragma unroll
    for (int dt = 0; dt < 2; ++dt)
        #pragma unroll
        for (int g = 0; g < 4; ++g) {
            u32 w0 = cvt_pk_bf16(ot[dt][4 * g] * inv,     ot[dt][4 * g + 1] * inv);
            u32 w1 = cvt_pk_bf16(ot[dt][4 * g + 2] * inv, ot[dt][4 * g + 3] * inv);
            int d0 = 8 * g + 4 * hi + 32 * dt;
            int byteoff = l31 * 128 + ((d0 * 2) ^ ((l31 & 7) << 4));
            uint2 pr; pr.x = w0; pr.y = w1;
            *(uint2*)((char*)tile + byteoff) = pr;
        }
    // same-wave write->read: compiler inserts lgkmcnt wait; tile is wave-private
    const size_t gbase = ((size_t)bh * SEQ + qbase) * DKH;
    #pragma unroll
    for (int p = 0; p < 4; ++p) {
        int q = p * 8 + (lane >> 3);
        int byteoff = q * 128 + (((lane & 7) * 16) ^ ((q & 7) << 4));
        bf16x8 val = *(const bf16x8*)((const char*)tile + byteoff);
        *(bf16x8*)&aoh[gbase + p * 512 + lane * 8] = val;
    }
#undef STAGE
}

extern "C" void kernel_launch(void* const* d_in, const int* in_sizes, int n_in,
                              void* d_out, int out_size, void* d_ws, size_t ws_size,
                              hipStream_t stream)
{
    const float* q  = (const float*)d_in[0];
    const float* k  = (const float*)d_in[1];
    const float* v  = (const float*)d_in[2];
    const float* Wq = (const float*)d_in[3];
    const float* bq = (const float*)d_in[4];
    const float* Wo = (const float*)d_in[5];
    const float* bo = (const float*)d_in[6];

    char* ws = (char*)d_ws;
    // layout (bytes): xb[0..24M) | wqt@24M | wot@26M | qh@28M | kh@36M | vh@44M
    // vt and aoh alias the xb region (xb dead after the projection GEMM).
    u16* xb  = (u16*)(ws);
    u16* wqt = (u16*)(ws + 25165824);
    u16* wot = (u16*)(ws + 27262976);
    u16* qh  = (u16*)(ws + 29360128);
    u16* kh  = qh + PER_SRC;
    u16* vh  = kh + PER_SRC;
    u16* vt  = (u16*)(ws);
    u16* aoh = (u16*)(ws + 8388608);

    cast_qkv<<<dim3(2048, 3), dim3(256), 0, stream>>>(q, k, v, xb);
    wtrans<<<dim3(256, 2), dim3(256), 0, stream>>>(Wq, Wo, wqt, wot);
    gemm_bt<0><<<dim3(256, 1, 3), dim3(256), 0, stream>>>(xb, wqt, bq, (void*)qh);
    vtrans<<<dim3(32, 32), dim3(256), 0, stream>>>(vh, vt);
    attn<<<dim3(512), dim3(256), 0, stream>>>(qh, kh, vt, aoh);
    gemm_bt<1><<<dim3(256), dim3(256), 0, stream>>>(aoh, wot, bo, d_out);
}